// Round 1
// baseline (214.874 us; speedup 1.0000x reference)
//
#include <hip/hip_runtime.h>

// LR_PINN_phase2_midout: fused 4-stage tiny MLP, N=262144, H=256, R=32.
// out = (tanh-chain of 3 low-rank blocks)(tanh(x*w0+t*w1+b)) @ end_w + end_b
//
// Design: fp16 MFMA 16x16x32 (fp32 accum), one wave = 16 points.
// Transposed GEMM forms so every MFMA D lands with point index = lane&15:
//   GEMM1: P^T[32x16] = C^T[32x256] . h^T[256x16]   (A=C^T from LDS, B=h from wave-private hbuf)
//   GEMM2: H^T[256x16] = R[256x32] . P^T[32x16]     (A=R from LDS,   B=P from wave-private pbuf)
// Wave-private LDS round-trips only need s_waitcnt lgkmcnt(0) (no barriers).
// All weights resident in LDS fp16: 138.5 KB -> 1 block/CU, persistent grid of 256.

typedef _Float16 half8   __attribute__((ext_vector_type(8)));
typedef _Float16 half4_t __attribute__((ext_vector_type(4)));
typedef float    float4_t __attribute__((ext_vector_type(4)));

namespace {

struct Smem {
  _Float16 ct[3][32 * 264];   // C^T with alpha folded: ct[k][r*264+j] = col_k[j][r]*alpha_k[r]; +8 pad -> uniform banks
  _Float16 rw[3][256 * 32];   // row_k natural layout [j][r]; stride 32 already bank-uniform for b128 at 8q
  float w0[256];              // start_w[:,0]
  float w1[256];              // start_w[:,1]
  float bb[256];              // start_b
  float ew[256];              // end_w
  _Float16 hbuf[4][16 * 264]; // per-wave h[m][j], stride 264
  _Float16 pbuf[4][16 * 32];  // per-wave P[m][r]
};

__device__ __forceinline__ float fast_tanh(float x) {
  // tanh(x) = 1 - 2/(1 + exp2(2*log2e*x)); v_exp_f32+v_rcp_f32, ~1e-7 abs err,
  // exact saturation at +-inf (rcp(inf)=0, rcp(1)=1).
  float e = __builtin_amdgcn_exp2f(x * 2.885390081777927f);
  return 1.0f - 2.0f * __builtin_amdgcn_rcpf(e + 1.0f);
}

__global__ __launch_bounds__(256) void pinn_fused(
    const float* __restrict__ xg, const float* __restrict__ tg,
    const float* __restrict__ sw, const float* __restrict__ sb,
    const float* __restrict__ ewp, const float* __restrict__ ebp,
    const float* __restrict__ c0, const float* __restrict__ c1,
    const float* __restrict__ c2, const float* __restrict__ r0,
    const float* __restrict__ r1, const float* __restrict__ r2,
    const float* __restrict__ a0, const float* __restrict__ a1,
    const float* __restrict__ a2, float* __restrict__ out, int iters)
{
  __shared__ Smem sm;
  const int tid = threadIdx.x;

  // ---- stage all weights fp32 -> fp16 LDS (once per block; ~200KB L2-hot reads) ----
  for (int k = 0; k < 3; ++k) {
    const float* ck = (k == 0) ? c0 : (k == 1) ? c1 : c2;
    const float* rk = (k == 0) ? r0 : (k == 1) ? r1 : r2;
    const float* ak = (k == 0) ? a0 : (k == 1) ? a1 : a2;
    for (int i = tid; i < 8192; i += 256) {
      const int j = i >> 5, r = i & 31;
      sm.ct[k][r * 264 + j] = (_Float16)(ck[i] * ak[r]);  // fold diag(alpha)
      sm.rw[k][i] = (_Float16)rk[i];
    }
  }
  sm.w0[tid] = sw[2 * tid];
  sm.w1[tid] = sw[2 * tid + 1];
  sm.bb[tid] = sb[tid];
  sm.ew[tid] = ewp[tid];
  __syncthreads();  // the only barrier

  const int wave = tid >> 6;
  const int lane = tid & 63;
  const int m = lane & 15;   // point index within wave tile (MFMA N / lane&15)
  const int q = lane >> 4;   // quad id (MFMA K-group)
  const float ebv = ebp[0];

  _Float16* hrow = &sm.hbuf[wave][m * 264];
  _Float16* prow = &sm.pbuf[wave][m * 32];

#pragma unroll 1
  for (int it = 0; it < iters; ++it) {
    const int n0 = (blockIdx.x * iters + it) * 64 + wave * 16;
    const float xm = xg[n0 + m];
    const float tm = tg[n0 + m];

    // ---- phase 0: h[m][j] = tanh(x*w0[j]+t*w1[j]+b[j]); lane covers j=16t+4q+{0..3} ----
#pragma unroll
    for (int t = 0; t < 16; ++t) {
      const int cb = t * 16 + 4 * q;
      const float4_t w0v = *(const float4_t*)&sm.w0[cb];  // 4 distinct addrs/instr -> LDS broadcast
      const float4_t w1v = *(const float4_t*)&sm.w1[cb];
      const float4_t bv  = *(const float4_t*)&sm.bb[cb];
      half4_t hv;
      hv.x = (_Float16)fast_tanh(xm * w0v.x + tm * w1v.x + bv.x);
      hv.y = (_Float16)fast_tanh(xm * w0v.y + tm * w1v.y + bv.y);
      hv.z = (_Float16)fast_tanh(xm * w0v.z + tm * w1v.z + bv.z);
      hv.w = (_Float16)fast_tanh(xm * w0v.w + tm * w1v.w + bv.w);
      *(half4_t*)&hrow[cb] = hv;  // ds_write_b64, uniform banks
    }
    asm volatile("s_waitcnt lgkmcnt(0)" ::: "memory");

    float ssum = 0.0f;
#pragma unroll 1
    for (int k = 0; k < 3; ++k) {
      const _Float16* ctk = sm.ct[k];
      const _Float16* rwk = sm.rw[k];

      // ---- GEMM1: P^T = C^T . h^T ; A-frag: Ct[16rt+lane&15][32s+8q+jj], B-frag: h[m][32s+8q+jj]
      half8 bfr[8];
#pragma unroll
      for (int s = 0; s < 8; ++s) bfr[s] = *(const half8*)&hrow[32 * s + 8 * q];
      float4_t acc0 = {0.f, 0.f, 0.f, 0.f};
      float4_t acc1 = {0.f, 0.f, 0.f, 0.f};
#pragma unroll
      for (int s = 0; s < 8; ++s) {
        const half8 af0 = *(const half8*)&ctk[m * 264 + 32 * s + 8 * q];
        acc0 = __builtin_amdgcn_mfma_f32_16x16x32_f16(af0, bfr[s], acc0, 0, 0, 0);
        const half8 af1 = *(const half8*)&ctk[(16 + m) * 264 + 32 * s + 8 * q];
        acc1 = __builtin_amdgcn_mfma_f32_16x16x32_f16(af1, bfr[s], acc1, 0, 0, 0);
      }
      // D = P^T: lane holds P[m=lane&15][r = 16rt+4q+reg] -> pack pairs, b64 to pbuf
      {
        const half4_t p0 = {(_Float16)acc0.x, (_Float16)acc0.y, (_Float16)acc0.z, (_Float16)acc0.w};
        const half4_t p1 = {(_Float16)acc1.x, (_Float16)acc1.y, (_Float16)acc1.z, (_Float16)acc1.w};
        *(half4_t*)&prow[4 * q]      = p0;
        *(half4_t*)&prow[16 + 4 * q] = p1;
      }
      asm volatile("s_waitcnt lgkmcnt(0)" ::: "memory");

      // ---- GEMM2: H^T = R . P^T ; A-frag: R[16t+lane&15][8q+jj], B-frag: P[m][8q+jj]
      const half8 pf = *(const half8*)&prow[8 * q];
      float4_t hacc[16];
#pragma unroll
      for (int t = 0; t < 16; ++t) {
        const half8 rf = *(const half8*)&rwk[(t * 16 + m) * 32 + 8 * q];
        const float4_t z4 = {0.f, 0.f, 0.f, 0.f};
        hacc[t] = __builtin_amdgcn_mfma_f32_16x16x32_f16(rf, pf, z4, 0, 0, 0);
      }
      // D = H^T: lane holds h[m=lane&15][j = 16t+4q+reg]
      if (k < 2) {
#pragma unroll
        for (int t = 0; t < 16; ++t) {
          half4_t hv;
          hv.x = (_Float16)fast_tanh(hacc[t].x);
          hv.y = (_Float16)fast_tanh(hacc[t].y);
          hv.z = (_Float16)fast_tanh(hacc[t].z);
          hv.w = (_Float16)fast_tanh(hacc[t].w);
          *(half4_t*)&hrow[t * 16 + 4 * q] = hv;
        }
        asm volatile("s_waitcnt lgkmcnt(0)" ::: "memory");
      } else {
        // fold end_w into the last tanh epilogue in fp32 (no fp16 rounding on final layer)
#pragma unroll
        for (int t = 0; t < 16; ++t) {
          const float4_t ev = *(const float4_t*)&sm.ew[t * 16 + 4 * q];
          ssum += fast_tanh(hacc[t].x) * ev.x + fast_tanh(hacc[t].y) * ev.y
                + fast_tanh(hacc[t].z) * ev.z + fast_tanh(hacc[t].w) * ev.w;
        }
      }
    }
    // reduce partial dot over the 4 quads (each handled 64 of 256 j's)
    ssum += __shfl_xor(ssum, 16);
    ssum += __shfl_xor(ssum, 32);
    if (lane < 16) out[n0 + m] = ssum + ebv;
  }
}

}  // namespace

extern "C" void kernel_launch(void* const* d_in, const int* in_sizes, int n_in,
                              void* d_out, int out_size, void* d_ws, size_t ws_size,
                              hipStream_t stream) {
  const float* xg  = (const float*)d_in[0];
  const float* tg  = (const float*)d_in[1];
  const float* sw  = (const float*)d_in[2];   // start_w [256,2]
  const float* sb  = (const float*)d_in[3];   // start_b [256]
  const float* ewp = (const float*)d_in[4];   // end_w [1,256]
  const float* ebp = (const float*)d_in[5];   // end_b [1]
  const float* c0  = (const float*)d_in[6];
  const float* c1  = (const float*)d_in[7];
  const float* c2  = (const float*)d_in[8];
  const float* r0  = (const float*)d_in[9];
  const float* r1  = (const float*)d_in[10];
  const float* r2  = (const float*)d_in[11];
  const float* a0  = (const float*)d_in[12];
  const float* a1  = (const float*)d_in[13];
  const float* a2  = (const float*)d_in[14];
  float* outp = (float*)d_out;

  const int n = in_sizes[0];            // 262144
  const int iters = n / (256 * 64);     // 16 tiles of 64 points per block

  pinn_fused<<<256, 256, 0, stream>>>(xg, tg, sw, sb, ewp, ebp,
                                      c0, c1, c2, r0, r1, r2, a0, a1, a2,
                                      outp, iters);
}

// Round 2
// 212.629 us; speedup vs baseline: 1.0106x; 1.0106x over previous
//
#include <hip/hip_runtime.h>

// LR_PINN_phase2_midout: fused 4-stage tiny MLP, N=262144, H=256, R=32.
// R2 design: mfma_f32_16x16x16f16 everywhere. With K=16, the MFMA C/D layout
// (col = lane&15 = point, row = 4*quad + reg) is IDENTICAL to the next MFMA's
// B-fragment layout (col n = lane&15, k = 4*quad + jj). So the entire chain
//   phase0 -> GEMM1 (P^T = Ct.h^T, K=256 as 16 MFMAs)
//          -> GEMM2 (H^T = R.P^T, K=32 as 2 MFMAs, 16 j-tiles)
//          -> tanh -> next GEMM1 ...
// is layout-closed in registers: ZERO LDS round-trips, zero barriers, zero
// cross-lane ops until the final 2-shuffle epilogue reduce.
// LDS holds only the weights (109 KB, conflict-free strides) -> one
// 1024-thread block per CU -> 16 waves/CU (4/SIMD) vs R1's 4 waves/CU.

typedef _Float16 half4_t __attribute__((ext_vector_type(4)));
typedef float    float4_t __attribute__((ext_vector_type(4)));

#define CT_S 260   // halfs; 130 dwords/row; bank(m*130*2 %32)=2m -> 16 distinct b64 bank-pairs
#define RW_S 36    // halfs; 18 dwords/row;  bank(18m%32) distinct (gcd(18,32)=2) -> conflict-free

namespace {

struct Smem {
  _Float16 ct[3][32 * CT_S];    // Ct[r][j] = col_k[j][r]*alpha_k[r]  (49.9 KB)
  _Float16 rw[3][256 * RW_S];   // R[j][r]                            (55.3 KB)
  float w0[256], w1[256], bb[256], ew[256];                         // (4 KB)
};

__device__ __forceinline__ float fast_tanh(float x) {
  // tanh(x) = 1 - 2/(1 + exp2(2*log2e*x)); exact saturation at +-inf.
  float e = __builtin_amdgcn_exp2f(x * 2.885390081777927f);
  return 1.0f - 2.0f * __builtin_amdgcn_rcpf(e + 1.0f);
}

__global__ __launch_bounds__(1024) void pinn_fused(
    const float* __restrict__ xg, const float* __restrict__ tg,
    const float* __restrict__ sw, const float* __restrict__ sb,
    const float* __restrict__ ewp, const float* __restrict__ ebp,
    const float* __restrict__ c0, const float* __restrict__ c1,
    const float* __restrict__ c2, const float* __restrict__ r0,
    const float* __restrict__ r1, const float* __restrict__ r2,
    const float* __restrict__ a0, const float* __restrict__ a1,
    const float* __restrict__ a2, float* __restrict__ out, int n)
{
  __shared__ Smem sm;
  const int tid = threadIdx.x;

  // ---- stage weights fp32 -> fp16 LDS (once per block) ----
  for (int k = 0; k < 3; ++k) {
    const float* ck = (k == 0) ? c0 : (k == 1) ? c1 : c2;
    const float* rk = (k == 0) ? r0 : (k == 1) ? r1 : r2;
    const float* ak = (k == 0) ? a0 : (k == 1) ? a1 : a2;
    for (int i = tid; i < 8192; i += 1024) {
      const int j = i >> 5, r = i & 31;
      sm.ct[k][r * CT_S + j] = (_Float16)(ck[i] * ak[r]);  // fold diag(alpha)
      sm.rw[k][j * RW_S + r] = (_Float16)rk[i];
    }
  }
  if (tid < 256) {
    sm.w0[tid] = sw[2 * tid];
    sm.w1[tid] = sw[2 * tid + 1];
    sm.bb[tid] = sb[tid];
    sm.ew[tid] = ewp[tid];
  }
  __syncthreads();  // the only barrier

  const int wave = tid >> 6;
  const int lane = tid & 63;
  const int m = lane & 15;   // point index (MFMA col / A-row / B-col = lane&15)
  const int q = lane >> 4;   // quad
  const float ebv = ebp[0];

  const int ct0 = m * CT_S + 4 * q;         // Ct rows 0..15  (acc0), + 16*t
  const int ct1 = (16 + m) * CT_S + 4 * q;  // Ct rows 16..31 (acc1), + 16*t
  const int rwo = m * RW_S + 4 * q;         // R row 16t+m: + 576*t (RW_S*16)
  const int wo  = 4 * q;                    // j = 16t + 4q + jj
  const int tiles = n >> 4;

  for (int g = blockIdx.x * 16 + wave; g < tiles; g += 4096) {
    const int n0 = g * 16;
    const float xm = xg[n0 + m];
    const float tm = tg[n0 + m];

    // ---- phase 0: h[m][16t+4q+jj] = tanh(x*w0+t*w1+b), directly in B-frag layout ----
    half4_t hb[16];
#pragma unroll
    for (int t = 0; t < 16; ++t) {
      const int cb = t * 16 + wo;
      const float4_t w0v = *(const float4_t*)&sm.w0[cb];  // broadcast reads, conflict-free
      const float4_t w1v = *(const float4_t*)&sm.w1[cb];
      const float4_t bv  = *(const float4_t*)&sm.bb[cb];
      half4_t h;
      h.x = (_Float16)fast_tanh(fmaf(xm, w0v.x, fmaf(tm, w1v.x, bv.x)));
      h.y = (_Float16)fast_tanh(fmaf(xm, w0v.y, fmaf(tm, w1v.y, bv.y)));
      h.z = (_Float16)fast_tanh(fmaf(xm, w0v.z, fmaf(tm, w1v.z, bv.z)));
      h.w = (_Float16)fast_tanh(fmaf(xm, w0v.w, fmaf(tm, w1v.w, bv.w)));
      hb[t] = h;
    }

    float ssum = 0.0f;
#pragma unroll 1
    for (int k = 0; k < 3; ++k) {
      const _Float16* ctk = sm.ct[k];
      const _Float16* rwk = sm.rw[k];

      // ---- GEMM1: P^T[32 x 16pts] = Ct . h^T, K=256 in 16 K-tiles ----
      float4_t acc0 = {0.f, 0.f, 0.f, 0.f};
      float4_t acc1 = {0.f, 0.f, 0.f, 0.f};
#pragma unroll
      for (int t = 0; t < 16; ++t) {
        const half4_t a0 = *(const half4_t*)&ctk[ct0 + 16 * t];
        const half4_t a1 = *(const half4_t*)&ctk[ct1 + 16 * t];
        acc0 = __builtin_amdgcn_mfma_f32_16x16x16f16(a0, hb[t], acc0, 0, 0, 0);
        acc1 = __builtin_amdgcn_mfma_f32_16x16x16f16(a1, hb[t], acc1, 0, 0, 0);
      }
      // D(acc0/acc1) is ALREADY the B-frag for GEMM2 (r = 4q+reg) -> just pack fp16.
      const half4_t pfA = {(_Float16)acc0.x, (_Float16)acc0.y, (_Float16)acc0.z, (_Float16)acc0.w};
      const half4_t pfB = {(_Float16)acc1.x, (_Float16)acc1.y, (_Float16)acc1.z, (_Float16)acc1.w};

      // ---- GEMM2: H^T[256 x 16pts] = R . P^T, 16 j-tiles x (2 MFMAs, K=32) ----
      if (k < 2) {
#pragma unroll
        for (int t = 0; t < 16; ++t) {
          const half4_t rA = *(const half4_t*)&rwk[rwo + 576 * t];       // r = 4q+jj
          const half4_t rB = *(const half4_t*)&rwk[rwo + 576 * t + 16];  // r = 16+4q+jj
          float4_t hc = {0.f, 0.f, 0.f, 0.f};
          hc = __builtin_amdgcn_mfma_f32_16x16x16f16(rA, pfA, hc, 0, 0, 0);
          hc = __builtin_amdgcn_mfma_f32_16x16x16f16(rB, pfB, hc, 0, 0, 0);
          // D layout (j = 16t+4q+reg) == next GEMM1 B-frag layout. tanh+pack in-lane.
          half4_t h;
          h.x = (_Float16)fast_tanh(hc.x);
          h.y = (_Float16)fast_tanh(hc.y);
          h.z = (_Float16)fast_tanh(hc.z);
          h.w = (_Float16)fast_tanh(hc.w);
          hb[t] = h;
        }
      } else {
        // last block: fold end_w dot-product into the tanh epilogue in fp32
#pragma unroll
        for (int t = 0; t < 16; ++t) {
          const half4_t rA = *(const half4_t*)&rwk[rwo + 576 * t];
          const half4_t rB = *(const half4_t*)&rwk[rwo + 576 * t + 16];
          float4_t hc = {0.f, 0.f, 0.f, 0.f};
          hc = __builtin_amdgcn_mfma_f32_16x16x16f16(rA, pfA, hc, 0, 0, 0);
          hc = __builtin_amdgcn_mfma_f32_16x16x16f16(rB, pfB, hc, 0, 0, 0);
          const float4_t ev = *(const float4_t*)&sm.ew[t * 16 + wo];
          ssum += fast_tanh(hc.x) * ev.x + fast_tanh(hc.y) * ev.y
                + fast_tanh(hc.z) * ev.z + fast_tanh(hc.w) * ev.w;
        }
      }
    }
    // each lane holds the partial dot over its j-subset; reduce over the 4 quads
    ssum += __shfl_xor(ssum, 16);
    ssum += __shfl_xor(ssum, 32);
    if (lane < 16) out[n0 + m] = ssum + ebv;
  }
}

}  // namespace

extern "C" void kernel_launch(void* const* d_in, const int* in_sizes, int n_in,
                              void* d_out, int out_size, void* d_ws, size_t ws_size,
                              hipStream_t stream) {
  const float* xg  = (const float*)d_in[0];
  const float* tg  = (const float*)d_in[1];
  const float* sw  = (const float*)d_in[2];
  const float* sb  = (const float*)d_in[3];
  const float* ewp = (const float*)d_in[4];
  const float* ebp = (const float*)d_in[5];
  const float* c0  = (const float*)d_in[6];
  const float* c1  = (const float*)d_in[7];
  const float* c2  = (const float*)d_in[8];
  const float* r0  = (const float*)d_in[9];
  const float* r1  = (const float*)d_in[10];
  const float* r2  = (const float*)d_in[11];
  const float* a0  = (const float*)d_in[12];
  const float* a1  = (const float*)d_in[13];
  const float* a2  = (const float*)d_in[14];
  float* outp = (float*)d_out;

  const int n = in_sizes[0];  // 262144

  pinn_fused<<<256, 1024, 0, stream>>>(xg, tg, sw, sb, ewp, ebp,
                                       c0, c1, c2, r0, r1, r2, a0, a1, a2,
                                       outp, n);
}